// Round 4
// baseline (368.082 us; speedup 1.0000x reference)
//
#include <hip/hip_runtime.h>

#define HID 128

typedef __attribute__((ext_vector_type(8))) short bf16x8;
typedef __attribute__((ext_vector_type(4))) float f32x4;
typedef __attribute__((ext_vector_type(8))) unsigned short u16x8;

static __device__ inline unsigned short f2bf(float f) {
  unsigned uu = __builtin_bit_cast(unsigned, f);
  uu = (uu + 0x7fffu + ((uu >> 16) & 1u)) >> 16;
  return (unsigned short)uu;
}
static __device__ inline float bf2f(unsigned short s) {
  return __builtin_bit_cast(float, ((unsigned)s) << 16);
}

static __device__ inline bf16x8 cvt8(float4 lo, float4 hi) {
  bf16x8 r;
  float vals[8] = {lo.x, lo.y, lo.z, lo.w, hi.x, hi.y, hi.z, hi.w};
#pragma unroll
  for (int i = 0; i < 8; ++i) r[i] = (short)f2bf(vals[i]);
  return r;
}

// h = (x @ W^T + b) / 256 via MFMA bf16, h stored as bf16.
// One wave computes 64 rows x 128 cols (4 m-tiles share each W fragment).
__global__ __launch_bounds__(256) void proj_mfma(
    const float* __restrict__ x, const float* __restrict__ W,
    const float* __restrict__ b, unsigned short* __restrict__ h, int N) {
  int wave = (int)((blockIdx.x * 256 + threadIdx.x) >> 6);
  int lane = threadIdx.x & 63;
  int m0 = wave * 64;
  if (m0 >= N) return;
  int row = lane & 15;
  int kg = lane >> 4;

  bf16x8 afrag[4][4];
#pragma unroll
  for (int mt = 0; mt < 4; ++mt) {
    int r = m0 + mt * 16 + row;
    int rc = r < N ? r : N - 1;
    const float* xrow = x + (size_t)rc * HID + kg * 8;
#pragma unroll
    for (int s = 0; s < 4; ++s) {
      float4 lo = *(const float4*)(xrow + s * 32);
      float4 hi = *(const float4*)(xrow + s * 32 + 4);
      afrag[mt][s] = cvt8(lo, hi);
    }
  }

  int crow0 = kg * 4;
#pragma unroll
  for (int nt = 0; nt < 8; ++nt) {
    int n0 = nt * 16;
    f32x4 acc[4];
#pragma unroll
    for (int mt = 0; mt < 4; ++mt) acc[mt] = (f32x4){0.f, 0.f, 0.f, 0.f};
    const float* wrow = W + (size_t)(n0 + row) * HID + kg * 8;
#pragma unroll
    for (int s = 0; s < 4; ++s) {
      float4 lo = *(const float4*)(wrow + s * 32);
      float4 hi = *(const float4*)(wrow + s * 32 + 4);
      bf16x8 bfrag = cvt8(lo, hi);
#pragma unroll
      for (int mt = 0; mt < 4; ++mt)
        acc[mt] = __builtin_amdgcn_mfma_f32_16x16x32_bf16(afrag[mt][s], bfrag, acc[mt], 0, 0, 0);
    }
    float bb = b[n0 + row];
    int ccol = n0 + row;
#pragma unroll
    for (int mt = 0; mt < 4; ++mt) {
#pragma unroll
      for (int r2 = 0; r2 < 4; ++r2) {
        int orow = m0 + mt * 16 + crow0 + r2;
        if (orow < N)
          h[(size_t)orow * HID + ccol] = f2bf((acc[mt][r2] + bb) * (1.0f / 256.0f));
      }
    }
  }
}

// Grid-strided, pipelined edge kernel.
// Work unit: (edge e, 8-column group q in 0..15). Thread processes all 3 c's.
__global__ __launch_bounds__(256) void edge_kernel(
    const float* __restrict__ v, const float* __restrict__ u,
    const int* __restrict__ src, const int* __restrict__ dst,
    const unsigned short* __restrict__ h, float* __restrict__ out,
    long long total) {
  const long long stride = (long long)gridDim.x * 256;
  long long idx = (long long)blockIdx.x * 256 + threadIdx.x;
  if (idx >= total) return;

  int e = (int)(idx >> 4);
  int s = src[e];
  int d = dst[e];

  for (;;) {
    long long nidx = idx + stride;
    bool has_next = nidx < total;
    int ns = 0, nd = 0;
    if (has_next) {  // prefetch next iteration's indices (hides gather chain)
      int ne = (int)(nidx >> 4);
      ns = src[ne];
      nd = dst[ne];
    }

    int q = (int)(idx & 15);  // 8-col group

    // h gathers (L3-resident bf16): 16B each
    u16x8 ha = *(const u16x8*)(h + (size_t)s * HID + q * 8);
    u16x8 hb = *(const u16x8*)(h + (size_t)d * HID + q * 8);

    // streaming v loads (nontemporal)
    const f32x4* vp = (const f32x4*)(v + (size_t)e * 3 * HID + q * 8);
    f32x4 v0a = __builtin_nontemporal_load(vp + 0);
    f32x4 v0b = __builtin_nontemporal_load(vp + 1);
    f32x4 v1a = __builtin_nontemporal_load(vp + 32);
    f32x4 v1b = __builtin_nontemporal_load(vp + 33);
    f32x4 v2a = __builtin_nontemporal_load(vp + 64);
    f32x4 v2b = __builtin_nontemporal_load(vp + 65);

    float u0 = u[(size_t)e * 3 + 0];
    float u1 = u[(size_t)e * 3 + 1];
    float u2 = u[(size_t)e * 3 + 2];

    float phi[8];
#pragma unroll
    for (int j = 0; j < 8; ++j) phi[j] = bf2f(ha[j]) - bf2f(hb[j]);

    f32x4 o0a, o0b, o1a, o1b, o2a, o2b;
#pragma unroll
    for (int j = 0; j < 4; ++j) {
      o0a[j] = (v0a[j] + u0 * phi[j]) * 0.5f;
      o0b[j] = (v0b[j] + u0 * phi[4 + j]) * 0.5f;
      o1a[j] = (v1a[j] + u1 * phi[j]) * 0.5f;
      o1b[j] = (v1b[j] + u1 * phi[4 + j]) * 0.5f;
      o2a[j] = (v2a[j] + u2 * phi[j]) * 0.5f;
      o2b[j] = (v2b[j] + u2 * phi[4 + j]) * 0.5f;
    }

    f32x4* op = (f32x4*)(out + (size_t)e * 3 * HID + q * 8);
    __builtin_nontemporal_store(o0a, op + 0);
    __builtin_nontemporal_store(o0b, op + 1);
    __builtin_nontemporal_store(o1a, op + 32);
    __builtin_nontemporal_store(o1b, op + 33);
    __builtin_nontemporal_store(o2a, op + 64);
    __builtin_nontemporal_store(o2b, op + 65);

    if (!has_next) break;
    idx = nidx;
    e = (int)(idx >> 4);
    s = ns;
    d = nd;
  }
}

extern "C" void kernel_launch(void* const* d_in, const int* in_sizes, int n_in,
                              void* d_out, int out_size, void* d_ws, size_t ws_size,
                              hipStream_t stream) {
  const float* x = (const float*)d_in[0];
  const float* v = (const float*)d_in[1];
  const float* u = (const float*)d_in[2];
  const float* W = (const float*)d_in[3];
  const float* b = (const float*)d_in[4];
  const int* src = (const int*)d_in[5];
  const int* dst = (const int*)d_in[6];
  float* out = (float*)d_out;

  const int N = in_sizes[0] / HID;  // 50000
  const int E = in_sizes[5];        // 500000

  unsigned short* h = (unsigned short*)d_ws;  // N*HID bf16 = 12.8 MB

  int nWaves = (N + 63) / 64;
  int proj_blocks = (nWaves + 3) / 4;
  proj_mfma<<<proj_blocks, 256, 0, stream>>>(x, W, b, h, N);

  long long total = (long long)E * 16;  // (e, q8) units
  int edge_blocks = 4096;               // grid-stride, ~8 iters/thread
  edge_kernel<<<edge_blocks, 256, 0, stream>>>(v, u, src, dst, h, out, total);
}

// Round 5
// 294.432 us; speedup vs baseline: 1.2501x; 1.2501x over previous
//
#include <hip/hip_runtime.h>

#define HID 128

typedef __attribute__((ext_vector_type(8))) short bf16x8;
typedef __attribute__((ext_vector_type(4))) float f32x4;
typedef __attribute__((ext_vector_type(4))) unsigned short u16x4;

static __device__ inline unsigned short f2bf(float f) {
  unsigned uu = __builtin_bit_cast(unsigned, f);
  uu = (uu + 0x7fffu + ((uu >> 16) & 1u)) >> 16;
  return (unsigned short)uu;
}
static __device__ inline float bf2f(unsigned short s) {
  return __builtin_bit_cast(float, ((unsigned)s) << 16);
}

static __device__ inline bf16x8 cvt8(float4 lo, float4 hi) {
  bf16x8 r;
  float vals[8] = {lo.x, lo.y, lo.z, lo.w, hi.x, hi.y, hi.z, hi.w};
#pragma unroll
  for (int i = 0; i < 8; ++i) r[i] = (short)f2bf(vals[i]);
  return r;
}

// h = (x @ W^T + b) / 256 via MFMA bf16, h stored as bf16.
// One wave computes 64 rows x 128 cols (4 m-tiles share each W fragment).
__global__ __launch_bounds__(256) void proj_mfma(
    const float* __restrict__ x, const float* __restrict__ W,
    const float* __restrict__ b, unsigned short* __restrict__ h, int N) {
  int wave = (int)((blockIdx.x * 256 + threadIdx.x) >> 6);
  int lane = threadIdx.x & 63;
  int m0 = wave * 64;
  if (m0 >= N) return;
  int row = lane & 15;
  int kg = lane >> 4;

  bf16x8 afrag[4][4];
#pragma unroll
  for (int mt = 0; mt < 4; ++mt) {
    int r = m0 + mt * 16 + row;
    int rc = r < N ? r : N - 1;
    const float* xrow = x + (size_t)rc * HID + kg * 8;
#pragma unroll
    for (int s = 0; s < 4; ++s) {
      float4 lo = *(const float4*)(xrow + s * 32);
      float4 hi = *(const float4*)(xrow + s * 32 + 4);
      afrag[mt][s] = cvt8(lo, hi);
    }
  }

  int crow0 = kg * 4;
#pragma unroll
  for (int nt = 0; nt < 8; ++nt) {
    int n0 = nt * 16;
    f32x4 acc[4];
#pragma unroll
    for (int mt = 0; mt < 4; ++mt) acc[mt] = (f32x4){0.f, 0.f, 0.f, 0.f};
    const float* wrow = W + (size_t)(n0 + row) * HID + kg * 8;
#pragma unroll
    for (int s = 0; s < 4; ++s) {
      float4 lo = *(const float4*)(wrow + s * 32);
      float4 hi = *(const float4*)(wrow + s * 32 + 4);
      bf16x8 bfrag = cvt8(lo, hi);
#pragma unroll
      for (int mt = 0; mt < 4; ++mt)
        acc[mt] = __builtin_amdgcn_mfma_f32_16x16x32_bf16(afrag[mt][s], bfrag, acc[mt], 0, 0, 0);
    }
    float bb = b[n0 + row];
    int ccol = n0 + row;
#pragma unroll
    for (int mt = 0; mt < 4; ++mt) {
#pragma unroll
      for (int r2 = 0; r2 < 4; ++r2) {
        int orow = m0 + mt * 16 + crow0 + r2;
        if (orow < N)
          h[(size_t)orow * HID + ccol] = f2bf((acc[mt][r2] + bb) * (1.0f / 256.0f));
      }
    }
  }
}

// out[e][c][:] = (v[e][c][:] + u[e][c] * (h[src[e]] - h[dst[e]])) * 0.5
// one thread per (edge, quad-of-4-columns): 32 threads cover an edge.
// v loads / out stores are nontemporal (streaming) so h stays cached.
__global__ __launch_bounds__(256) void edge_kernel(
    const float* __restrict__ v, const float* __restrict__ u,
    const int* __restrict__ src, const int* __restrict__ dst,
    const unsigned short* __restrict__ h, float* __restrict__ out, int E) {
  int idx = blockIdx.x * 256 + threadIdx.x;
  int e = idx >> 5;
  if (e >= E) return;
  int q = idx & 31;

  int s = src[e];
  int d = dst[e];

  u16x4 a = *(const u16x4*)(h + (size_t)s * HID + q * 4);
  u16x4 bq = *(const u16x4*)(h + (size_t)d * HID + q * 4);
  float phix = bf2f(a.x) - bf2f(bq.x);
  float phiy = bf2f(a.y) - bf2f(bq.y);
  float phiz = bf2f(a.z) - bf2f(bq.z);
  float phiw = bf2f(a.w) - bf2f(bq.w);

  float u0 = u[(size_t)e * 3 + 0];
  float u1 = u[(size_t)e * 3 + 1];
  float u2 = u[(size_t)e * 3 + 2];

  const f32x4* vp = (const f32x4*)(v + (size_t)e * 3 * HID);
  f32x4* op = (f32x4*)(out + (size_t)e * 3 * HID);

  f32x4 v0 = __builtin_nontemporal_load(vp + q);
  f32x4 v1 = __builtin_nontemporal_load(vp + 32 + q);
  f32x4 v2 = __builtin_nontemporal_load(vp + 64 + q);

  f32x4 o0, o1, o2;
  o0[0] = (v0[0] + u0 * phix) * 0.5f;
  o0[1] = (v0[1] + u0 * phiy) * 0.5f;
  o0[2] = (v0[2] + u0 * phiz) * 0.5f;
  o0[3] = (v0[3] + u0 * phiw) * 0.5f;
  o1[0] = (v1[0] + u1 * phix) * 0.5f;
  o1[1] = (v1[1] + u1 * phiy) * 0.5f;
  o1[2] = (v1[2] + u1 * phiz) * 0.5f;
  o1[3] = (v1[3] + u1 * phiw) * 0.5f;
  o2[0] = (v2[0] + u2 * phix) * 0.5f;
  o2[1] = (v2[1] + u2 * phiy) * 0.5f;
  o2[2] = (v2[2] + u2 * phiz) * 0.5f;
  o2[3] = (v2[3] + u2 * phiw) * 0.5f;

  __builtin_nontemporal_store(o0, op + q);
  __builtin_nontemporal_store(o1, op + 32 + q);
  __builtin_nontemporal_store(o2, op + 64 + q);
}

extern "C" void kernel_launch(void* const* d_in, const int* in_sizes, int n_in,
                              void* d_out, int out_size, void* d_ws, size_t ws_size,
                              hipStream_t stream) {
  const float* x = (const float*)d_in[0];
  const float* v = (const float*)d_in[1];
  const float* u = (const float*)d_in[2];
  const float* W = (const float*)d_in[3];
  const float* b = (const float*)d_in[4];
  const int* src = (const int*)d_in[5];
  const int* dst = (const int*)d_in[6];
  float* out = (float*)d_out;

  const int N = in_sizes[0] / HID;  // 50000
  const int E = in_sizes[5];        // 500000

  unsigned short* h = (unsigned short*)d_ws;  // N*HID bf16 = 12.8 MB

  int nWaves = (N + 63) / 64;
  int proj_blocks = (nWaves + 3) / 4;
  proj_mfma<<<proj_blocks, 256, 0, stream>>>(x, W, b, h, N);

  long long total = (long long)E * 32;
  int edge_blocks = (int)((total + 255) / 256);
  edge_kernel<<<edge_blocks, 256, 0, stream>>>(v, u, src, dst, h, out, E);
}